// Round 17
// baseline (9239.478 us; speedup 1.0000x reference)
//
#include <hip/hip_runtime.h>
#include <stdint.h>

typedef unsigned int u32;
typedef unsigned short u16;

#define TT 256

// ---- weight layout (r8-proven, prep byte-identical) ----
#define LSW 272                         // LSTM row width in u32 words (544 slots)
#define OFF_L0  (2048*LSW)              // 557056
#define OFF_L1  (OFF_L0 + 864*128)      // 667648
#define OFF_L2  (OFF_L1 + 576*192)      // 778240
#define OFF_HL  (OFF_L2 + 640*160)      // 880640  h_lstm exchange: [128][264] u32 (u16[528])
#define OFF_REC (OFF_HL + 128*264)      // 914432  h_rec  exchange: [128][264] u32
#define OFF_SYNC (OFF_REC + 128*264)    // 948224  flags: [32 quads][8 slices][16 words]
#define WS_TOTAL (OFF_SYNC + 4096)      // 952320 u32 ≈ 3.63 MiB
#define NFL 16

__device__ __forceinline__ u16 f2bf(float f){
  u32 u = __builtin_bit_cast(u32, f);
  u += 0x7FFFu + ((u >> 16) & 1u);      // RNE
  return (u16)(u >> 16);
}
__device__ __forceinline__ u32 packbf(float lo, float hi){
  return (u32)f2bf(lo) | ((u32)f2bf(hi) << 16);
}
__device__ __forceinline__ float bdot(u32 a, u32 b, float c){
  float d;
  asm("v_dot2_f32_bf16 %0, %1, %2, %3" : "=v"(d) : "v"(a), "v"(b), "v"(c));
  return d;
}
__device__ __forceinline__ float sigm(float x){ return 1.0f/(1.0f + __expf(-x)); }
__device__ __forceinline__ float tanh_(float x){ return 1.0f - 2.0f/(1.0f + __expf(2.0f*x)); }

// cross-XCD exchange: agent-scope relaxed atomics at the L3 coherence point
// (r8-proven; sc0-load shortcuts are UNSOUND — r10-12).
__device__ __forceinline__ u32 xload(const u32* p){
  return __hip_atomic_load(p, __ATOMIC_RELAXED, __HIP_MEMORY_SCOPE_AGENT);
}
__device__ __forceinline__ void xstore16(u16* p, u16 v){
  __hip_atomic_store(p, v, __ATOMIC_RELAXED, __HIP_MEMORY_SCOPE_AGENT);
}

// Flag barrier (r8-proven): monotonic per-(quad,slice) flag, no RMW.
__device__ __forceinline__ void bar_arrive(u32* fl, int s, u32 v){
  __syncthreads();
  if (threadIdx.x == 0)
    __hip_atomic_store(&fl[s*NFL], v, __ATOMIC_RELAXED, __HIP_MEMORY_SCOPE_AGENT);
}
__device__ __forceinline__ void bar_wait(const u32* fl, u32 v){
  if (threadIdx.x < 8){
    int guard = 1 << 16;
    while (__hip_atomic_load(&fl[threadIdx.x*NFL], __ATOMIC_RELAXED, __HIP_MEMORY_SCOPE_AGENT) < v
           && --guard) __builtin_amdgcn_s_sleep(1);
  }
  __syncthreads();
  asm volatile("" ::: "memory");
}

// ---------------- weight value mappings (r8-proven) ----------------
__device__ __forceinline__ float lstmval(const float* wi, const float* wr, int r, int s){
  if (s < 9)  return wi[r*9 + s];
  if (s == 9 || s == 369 || s >= 523) return 0.f;
  if (s < 369) return wr[r*512 + s - 10];   // h0..h358
  return wr[r*512 + s - 11];                // h359..h511
}
__device__ __forceinline__ float l0val(const float* W, const int* M, int o, int k){
  if (k == 9 || k >= 226) return 0.f;
  int ki = (k < 9) ? k : k - 1;                 // D=225
  float w = W[o*225 + ki];
  if (M) w *= (float)M[o*225 + ki];
  return w;
}
__device__ __forceinline__ float l1val(const float* W, const int* M, int o, int k){
  if (k >= 359) return 0.f;                     // D=359
  float w = W[o*359 + k];
  if (M) w *= (float)M[o*359 + k];
  return w;
}
__device__ __forceinline__ float l2val(const float* W, const int* M, int o, int k){
  if (k == 143 || k == 144 || k >= 298) return 0.f;  // D=296; slot144 = h358 (zero weight)
  int ki = (k < 143) ? k : k - 2;
  float w = W[o*296 + ki];
  if (M) w *= (float)M[o*296 + ki];
  return w;
}

__global__ void prep_kernel(
    const float* __restrict__ wi, const float* __restrict__ wr,
    const float* __restrict__ w10,const float* __restrict__ w20,const float* __restrict__ wa0,const float* __restrict__ wb0,const int* __restrict__ m0,
    const float* __restrict__ w11,const float* __restrict__ w21,const float* __restrict__ wa1,const float* __restrict__ wb1,const int* __restrict__ m1,
    const float* __restrict__ w12,const float* __restrict__ w22,const float* __restrict__ wa2,const float* __restrict__ wb2,const int* __restrict__ m2,
    u32* __restrict__ ws)
{
  for (int i = blockIdx.x*blockDim.x + threadIdx.x; i < WS_TOTAL; i += gridDim.x*blockDim.x){
    float lo = 0.f, hi = 0.f;
    if (i < OFF_L0){
      int row = i / LSW, k2 = i - row*LSW;
      int orig = (row >> 2) + ((row & 3) << 9);   // gate-interleaved rows: r=4v+g
      lo = lstmval(wi, wr, orig, 2*k2);
      hi = lstmval(wi, wr, orig, 2*k2+1);
    } else if (i < OFF_L1){
      int loc = i - OFF_L0;
      int row = loc >> 7, k2 = loc & 127;
      int o = row >> 2, m = row & 3;
      const float* W = (m==0)?w10:(m==1)?w20:(m==2)?wa0:wb0;
      const int* M = (m < 2) ? m0 : nullptr;
      lo = l0val(W, M, o, 2*k2); hi = l0val(W, M, o, 2*k2+1);
    } else if (i < OFF_L2){
      int loc = i - OFF_L1;
      int row = loc / 192, k2 = loc - row*192;
      int o = row >> 2, m = row & 3;
      if (o < 143){
        const float* W = (m==0)?w11:(m==1)?w21:(m==2)?wa1:wb1;
        const int* M = (m < 2) ? m1 : nullptr;
        lo = l1val(W, M, o, 2*k2); hi = l1val(W, M, o, 2*k2+1);
      }
    } else if (i < OFF_HL){
      int loc = i - OFF_L2;
      int row = loc / 160, k2 = loc - row*160;
      int o = row >> 2, m = row & 3;
      if (o < 153){
        const float* W = (m==0)?w12:(m==1)?w22:(m==2)?wa2:wb2;
        const int* M = (m < 2) ? m2 : nullptr;
        lo = l2val(W, M, o, 2*k2); hi = l2val(W, M, o, 2*k2+1);
      }
    } else {
      ws[i] = 0u;                 // exchange arrays (h(0)=0) + flags
      continue;
    }
    ws[i] = packbf(lo, hi);
  }
}

// ---------------- 3-hop sliced kernel: r8 with ONLY phase D made redundant ----
// grid 256 = 8 slices x 32 quads (r8 mapping). A, B, C sliced with hops exactly
// as r8. D computed REDUNDANTLY per block (thread rr = output, same k-order,
// same staged input words 0..159 as r8's sliced D) -> i2 kept in block-local
// LDS (i2l), consumed by next step's A staging. Removes r8's bar 4 and its
// top-of-loop wait: i0(t-1) stable since bar2(t-1) [wait passed in C staging],
// i1(t-1) stable since bar3(t-1) [wait passed in D staging], i2 block-local.
__global__ __launch_bounds__(1024) void liquid_rnn(
    const float* __restrict__ x, const float* __restrict__ dtp,
    const float* __restrict__ lstm_bi,
    const float* __restrict__ b10, const float* __restrict__ b20,
    const float* __restrict__ ba0, const float* __restrict__ bb0,
    const float* __restrict__ b11, const float* __restrict__ b21,
    const float* __restrict__ ba1, const float* __restrict__ bb1,
    const float* __restrict__ b12, const float* __restrict__ b22,
    const float* __restrict__ ba2, const float* __restrict__ bb2,
    u32* __restrict__ ws, float* __restrict__ out)
{
  __shared__ u32 xcS[4][272];     // activation staging (per local batch)
  __shared__ u32 i2l[4][78];      // block-local i2 (u16[156]: i2[0..152], pads 0)

  const int tid  = threadIdx.x;
  const int bid  = blockIdx.x;
  const int s    = bid & 7;
  const int quad = bid >> 3;
  const int b4   = tid & 3;
  const int rr   = tid >> 2;            // 0..255
  const int batch= quad*4 + b4;

  u32* hlw  = ws + OFF_HL;
  u32* recw = ws + OFF_REC;
  u16* hl16 = (u16*)hlw;
  u16* rec16= (u16*)recw;
  u32* fl   = ws + OFF_SYNC + quad*(8*NFL);

  // ---- hoisted per-thread constants (A/B/C as r8; D redundant) ----
  const int vA = s*64 + (rr >> 2);
  const float lb = lstm_bi[vA + 512*(rr & 3)];
  int oB = 0; float biasB = 0.f;
  if (tid < 432){ int m = rr & 3; oB = 27*s + (rr >> 2);
    biasB = ((m==0)?b10:(m==1)?b20:(m==2)?ba0:bb0)[oB]; }
  int oC = 0; float biasC = 0.f;
  if (tid < 288){ int m = rr & 3; oC = 18*s + (rr >> 2);
    if (oC < 143) biasC = ((m==0)?b11:(m==1)?b21:(m==2)?ba1:bb1)[oC]; }
  float bD1=0,bD2=0,bDa=0,bDb=0;        // redundant D: thread rr = output
  if (rr < 153){ bD1=b12[rr]; bD2=b22[rr]; bDa=ba2[rr]; bDb=bb2[rr]; }

  for (int i = tid; i < 4*272; i += 1024) ((u32*)xcS)[i] = 0u;
  for (int i = tid; i < 4*78;  i += 1024) ((u32*)i2l)[i] = 0u;
  float creg = 0.f;
  __syncthreads();

  for (int t = 0; t < TT; ++t){
    const u32 vb = 3u*(u32)t;
    // ========== top staging (no wait: see kernel comment) ==========
    if (tid < 20){                              // xt words 0..4
      int bb = tid/5, w = tid - bb*5;
      int bg = quad*4 + bb;
      float e0, e1;
      if (w < 4){ e0 = x[((size_t)bg*TT + t)*8 + 2*w]; e1 = x[((size_t)bg*TT + t)*8 + 2*w+1]; }
      else      { e0 = dtp[(size_t)bg*TT + t]; e1 = 0.f; }
      xcS[bb][w] = packbf(e0, e1);
    }
    if (tid < 720){                             // i0,i1 pairs -> words 5..184 (r8)
      int bb = tid/180, j = tid - bb*180;
      xcS[bb][5+j] = xload(&recw[(size_t)(quad*4+bb)*264 + j]);
    }
    if (tid < 308){                             // i2 from block-local i2l -> words 185..261
      int bb = tid/77, k = tid - bb*77;
      xcS[bb][185+k] = i2l[bb][k];
    }
    __syncthreads();
    // ================= phase A: LSTM sliced (r8 verbatim) =================
    {
      float A = lb;
      const u32* wrow = ws + (size_t)(s*256 + rr)*LSW;
      #pragma unroll 4
      for (int g = 0; g < 68; ++g){
        uint4 wv = *(const uint4*)(wrow + (g<<2));
        uint4 av = *(const uint4*)&xcS[b4][g<<2];
        A = bdot(wv.x, av.x, A); A = bdot(wv.y, av.y, A);
        A = bdot(wv.z, av.z, A); A = bdot(wv.w, av.w, A);
      }
      float zig = __shfl_down(A, 4), zfg = __shfl_down(A, 8), zog = __shfl_down(A, 12);
      if (!(rr & 3)){
        creg = creg * sigm(zfg + 1.0f) + tanh_(A) * sigm(zig);
        float hl = tanh_(creg) * sigm(zog);
        xstore16(&hl16[(size_t)batch*528 + vA], f2bf(hl));
      }
    }
    bar_arrive(fl, s, vb+1);  bar_wait(fl, vb+1);
    // ================= phase B: CfC L0 sliced (r8 verbatim) =================
    if (tid < 432){ int bb = tid/108, j = tid - bb*108;       // hl pairs 0..107
      xcS[bb][5+j] = xload(&hlw[(size_t)(quad*4+bb)*264 + j]); }
    __syncthreads();
    if (tid < 432){
      float A = biasB;
      const u32* wrow = ws + OFF_L0 + (size_t)(s*108 + rr)*128;
      #pragma unroll 2
      for (int g = 0; g < 30; ++g){
        uint4 wv = *(const uint4*)(wrow + (g<<2));
        uint4 av = *(const uint4*)&xcS[b4][g<<2];
        A = bdot(wv.x, av.x, A); A = bdot(wv.y, av.y, A);
        A = bdot(wv.z, av.z, A); A = bdot(wv.w, av.w, A);
      }
      float A1 = __shfl_down(A, 4), A2 = __shfl_down(A, 8), A3 = __shfl_down(A, 12);
      if (!(rr & 3)){
        float ti = sigm(A3 - A2);
        float o0 = tanh_(A)*(1.f - ti) + ti*tanh_(A1);
        xstore16(&rec16[(size_t)batch*528 + oB], f2bf(o0));
        if (t == TT-1) out[(size_t)batch*512 + oB] = o0;
      }
    }
    bar_arrive(fl, s, vb+2);  bar_wait(fl, vb+2);
    // ================= phase C: CfC L1 sliced (r8 verbatim) =================
    if (tid < 720){ int bb = tid/180, j = tid - bb*180;
      u32 v = (j < 108) ? xload(&recw[(size_t)(quad*4+bb)*264 + j])    // i0 pairs
                        : xload(&hlw[(size_t)(quad*4+bb)*264 + j]);    // hl 108..179
      xcS[bb][j] = v; }
    __syncthreads();
    if (tid < 288){
      float A = biasC;
      const u32* wrow = ws + OFF_L1 + (size_t)(s*72 + rr)*192;
      #pragma unroll 4
      for (int g = 0; g < 48; ++g){
        uint4 wv = *(const uint4*)(wrow + (g<<2));
        uint4 av = *(const uint4*)&xcS[b4][g<<2];
        A = bdot(wv.x, av.x, A); A = bdot(wv.y, av.y, A);
        A = bdot(wv.z, av.z, A); A = bdot(wv.w, av.w, A);
      }
      float A1 = __shfl_down(A, 4), A2 = __shfl_down(A, 8), A3 = __shfl_down(A, 12);
      if (!(rr & 3) && oC < 143){
        float ti = sigm(A3 - A2);
        float o0 = tanh_(A)*(1.f - ti) + ti*tanh_(A1);
        xstore16(&rec16[(size_t)batch*528 + 216 + oC], f2bf(o0));
        if (t == TT-1) out[(size_t)batch*512 + 216 + oC] = o0;
      }
    }
    bar_arrive(fl, s, vb+3);  bar_wait(fl, vb+3);
    // ================= phase D: CfC L2 REDUNDANT (staging r8 verbatim) =====
    if (tid < 596){ int bb = tid/149, j = tid - bb*149;
      u32 v;
      if (j < 72)      v = xload(&recw[(size_t)(quad*4+bb)*264 + 108 + j]);  // i1
      else if (j == 72) v = xload(&hlw[(size_t)(quad*4+bb)*264 + 179]);      // (h358,h359)
      else              v = xload(&hlw[(size_t)(quad*4+bb)*264 + 180 + (j-73)]);
      xcS[bb][j] = v; }
    __syncthreads();
    if (tid < 612){                             // thread rr = output (rr<153), all 4 dots
      float A0=bD1, A1=bD2, A2=bDa, A3=bDb;
      const u32* p = ws + OFF_L2 + (size_t)(4*rr)*160;   // rows 4o+m, o=rr
      #pragma unroll 4
      for (int g = 0; g < 40; ++g){
        uint4 av = *(const uint4*)&xcS[b4][g<<2];
        uint4 w0 = *(const uint4*)(p + (g<<2));
        uint4 w1 = *(const uint4*)(p + 160 + (g<<2));
        uint4 w2 = *(const uint4*)(p + 320 + (g<<2));
        uint4 w3 = *(const uint4*)(p + 480 + (g<<2));
        A0=bdot(w0.x,av.x,A0); A0=bdot(w0.y,av.y,A0); A0=bdot(w0.z,av.z,A0); A0=bdot(w0.w,av.w,A0);
        A1=bdot(w1.x,av.x,A1); A1=bdot(w1.y,av.y,A1); A1=bdot(w1.z,av.z,A1); A1=bdot(w1.w,av.w,A1);
        A2=bdot(w2.x,av.x,A2); A2=bdot(w2.y,av.y,A2); A2=bdot(w2.z,av.z,A2); A2=bdot(w2.w,av.w,A2);
        A3=bdot(w3.x,av.x,A3); A3=bdot(w3.y,av.y,A3); A3=bdot(w3.z,av.z,A3); A3=bdot(w3.w,av.w,A3);
      }
      float ti = sigm(A3 - A2);
      float o0 = tanh_(A0)*(1.f - ti) + ti*tanh_(A1);
      ((u16*)i2l[b4])[rr] = f2bf(o0);           // i2 -> block-local (slots 153..155 stay 0)
      if (t == TT-1) out[(size_t)batch*512 + 359 + rr] = o0;
    }
    __syncthreads();                            // i2l ready for next step's top staging
  }

  if (!(rr & 3)) out[65536 + (size_t)batch*512 + vA] = creg;
}

extern "C" void kernel_launch(void* const* d_in, const int* in_sizes, int n_in,
                              void* d_out, int out_size, void* d_ws, size_t ws_size,
                              hipStream_t stream)
{
  (void)in_sizes; (void)n_in; (void)out_size; (void)ws_size;
  const float* x   = (const float*)d_in[0];
  const float* dt  = (const float*)d_in[1];
  const float* wi  = (const float*)d_in[2];
  const float* wr  = (const float*)d_in[3];
  const float* bi  = (const float*)d_in[4];
  const float* w10 = (const float*)d_in[5];  const float* b10 = (const float*)d_in[6];
  const float* w20 = (const float*)d_in[7];  const float* b20 = (const float*)d_in[8];
  const float* wa0 = (const float*)d_in[9];  const float* ba0 = (const float*)d_in[10];
  const float* wb0 = (const float*)d_in[11]; const float* bb0 = (const float*)d_in[12];
  const float* w11 = (const float*)d_in[13]; const float* b11 = (const float*)d_in[14];
  const float* w21 = (const float*)d_in[15]; const float* b21 = (const float*)d_in[16];
  const float* wa1 = (const float*)d_in[17]; const float* ba1 = (const float*)d_in[18];
  const float* wb1 = (const float*)d_in[19]; const float* bb1 = (const float*)d_in[20];
  const float* w12 = (const float*)d_in[21]; const float* b12 = (const float*)d_in[22];
  const float* w22 = (const float*)d_in[23]; const float* b22 = (const float*)d_in[24];
  const float* wa2 = (const float*)d_in[25]; const float* ba2 = (const float*)d_in[26];
  const float* wb2 = (const float*)d_in[27]; const float* bb2 = (const float*)d_in[28];
  const int* m0 = (const int*)d_in[29];
  const int* m1 = (const int*)d_in[30];
  const int* m2 = (const int*)d_in[31];

  u32* ws    = (u32*)d_ws;         // needs WS_TOTAL*4 ≈ 3.63 MiB
  float* out = (float*)d_out;      // f32: h[128*512] then c[128*512]

  prep_kernel<<<dim3(931), dim3(1024), 0, stream>>>(
      wi, wr,
      w10,w20,wa0,wb0,m0,
      w11,w21,wa1,wb1,m1,
      w12,w22,wa2,wb2,m2,
      ws);

  liquid_rnn<<<dim3(256), dim3(1024), 0, stream>>>(
      x, dt, bi,
      b10,b20,ba0,bb0,
      b11,b21,ba1,bb1,
      b12,b22,ba2,bb2,
      ws, out);
}

// Round 20
// 6022.502 us; speedup vs baseline: 1.5342x; 1.5342x over previous
//
#include <hip/hip_runtime.h>
#include <stdint.h>

typedef unsigned int u32;
typedef unsigned short u16;

#define TT 256

// ---- weight layout: all regions row-major [row][K-words] ----
#define LSW 272                         // LSTM row width in u32 words (544 slots)
#define OFF_L0  (2048*LSW)              // 557056
#define OFF_L1  (OFF_L0 + 864*128)      // 667648
#define OFF_L2  (OFF_L1 + 576*192)      // 778240
#define OFF_HL  (OFF_L2 + 640*160)      // 880640  h_lstm exchange: [128][264] u32 (u16[528])
#define OFF_REC (OFF_HL + 128*264)      // 914432  h_rec  exchange: [128][264] u32
#define OFF_SYNC (OFF_REC + 128*264)    // 948224  flags: [32 quads][8 slices][16 words]
#define WS_TOTAL (OFF_SYNC + 4096)      // 952320 u32 ≈ 3.63 MiB
#define NFL 16                          // flag padding: 64 B per block -> no RMW contention

__device__ __forceinline__ u16 f2bf(float f){
  u32 u = __builtin_bit_cast(u32, f);
  u += 0x7FFFu + ((u >> 16) & 1u);      // RNE
  return (u16)(u >> 16);
}
__device__ __forceinline__ u32 packbf(float lo, float hi){
  return (u32)f2bf(lo) | ((u32)f2bf(hi) << 16);
}
__device__ __forceinline__ float bdot(u32 a, u32 b, float c){
  float d;
  asm("v_dot2_f32_bf16 %0, %1, %2, %3" : "=v"(d) : "v"(a), "v"(b), "v"(c));
  return d;
}
__device__ __forceinline__ float sigm(float x){ return 1.0f/(1.0f + __expf(-x)); }
__device__ __forceinline__ float tanh_(float x){ return 1.0f - 2.0f/(1.0f + __expf(2.0f*x)); }

// cross-XCD exchange: agent-scope relaxed atomics act at the coherence point
// (L3), so visibility never depends on XCD placement (G16).
__device__ __forceinline__ u32 xload(const u32* p){
  return __hip_atomic_load(p, __ATOMIC_RELAXED, __HIP_MEMORY_SCOPE_AGENT);
}
__device__ __forceinline__ void xstore16(u16* p, u16 v){
  __hip_atomic_store(p, v, __ATOMIC_RELAXED, __HIP_MEMORY_SCOPE_AGENT);
}

// Flag barrier (monotonic, per-block flag line -> no RMW serialization).
// arrive: __syncthreads drains every wave's data stores (compiler emits
// s_waitcnt vmcnt(0) before s_barrier) => data globally visible, then one
// relaxed flag store. wait: lanes 0..7 poll the 8 quad flags in parallel
// (one gather/iter); bounded spin -> hang impossible.
__device__ __forceinline__ void bar_arrive(u32* fl, int s, u32 v){
  __syncthreads();
  if (threadIdx.x == 0)
    __hip_atomic_store(&fl[s*NFL], v, __ATOMIC_RELAXED, __HIP_MEMORY_SCOPE_AGENT);
}
__device__ __forceinline__ void bar_wait(const u32* fl, u32 v){
  if (threadIdx.x < 8){
    int guard = 1 << 16;
    while (__hip_atomic_load(&fl[threadIdx.x*NFL], __ATOMIC_RELAXED, __HIP_MEMORY_SCOPE_AGENT) < v
           && --guard) __builtin_amdgcn_s_sleep(1);
  }
  __syncthreads();
  asm volatile("" ::: "memory");
}

// ---------------- weight value mappings (proven rounds 3-8) ----------------
__device__ __forceinline__ float lstmval(const float* wi, const float* wr, int r, int s){
  if (s < 9)  return wi[r*9 + s];
  if (s == 9 || s == 369 || s >= 523) return 0.f;
  if (s < 369) return wr[r*512 + s - 10];   // h0..h358
  return wr[r*512 + s - 11];                // h359..h511
}
__device__ __forceinline__ float l0val(const float* W, const int* M, int o, int k){
  if (k == 9 || k >= 226) return 0.f;
  int ki = (k < 9) ? k : k - 1;                 // D=225
  float w = W[o*225 + ki];
  if (M) w *= (float)M[o*225 + ki];
  return w;
}
__device__ __forceinline__ float l1val(const float* W, const int* M, int o, int k){
  if (k >= 359) return 0.f;                     // D=359
  float w = W[o*359 + k];
  if (M) w *= (float)M[o*359 + k];
  return w;
}
__device__ __forceinline__ float l2val(const float* W, const int* M, int o, int k){
  if (k == 143 || k == 144 || k >= 298) return 0.f;  // D=296; slot144 = h358 (zero weight)
  int ki = (k < 143) ? k : k - 2;
  float w = W[o*296 + ki];
  if (M) w *= (float)M[o*296 + ki];
  return w;
}

__global__ void prep_kernel(
    const float* __restrict__ wi, const float* __restrict__ wr,
    const float* __restrict__ w10,const float* __restrict__ w20,const float* __restrict__ wa0,const float* __restrict__ wb0,const int* __restrict__ m0,
    const float* __restrict__ w11,const float* __restrict__ w21,const float* __restrict__ wa1,const float* __restrict__ wb1,const int* __restrict__ m1,
    const float* __restrict__ w12,const float* __restrict__ w22,const float* __restrict__ wa2,const float* __restrict__ wb2,const int* __restrict__ m2,
    u32* __restrict__ ws)
{
  for (int i = blockIdx.x*blockDim.x + threadIdx.x; i < WS_TOTAL; i += gridDim.x*blockDim.x){
    float lo = 0.f, hi = 0.f;
    if (i < OFF_L0){
      int row = i / LSW, k2 = i - row*LSW;
      int orig = (row >> 2) + ((row & 3) << 9);   // gate-interleaved rows: r=4v+g
      lo = lstmval(wi, wr, orig, 2*k2);
      hi = lstmval(wi, wr, orig, 2*k2+1);
    } else if (i < OFF_L1){
      int loc = i - OFF_L0;
      int row = loc >> 7, k2 = loc & 127;
      int o = row >> 2, m = row & 3;
      const float* W = (m==0)?w10:(m==1)?w20:(m==2)?wa0:wb0;
      const int* M = (m < 2) ? m0 : nullptr;
      lo = l0val(W, M, o, 2*k2); hi = l0val(W, M, o, 2*k2+1);
    } else if (i < OFF_L2){
      int loc = i - OFF_L1;
      int row = loc / 192, k2 = loc - row*192;
      int o = row >> 2, m = row & 3;
      if (o < 143){
        const float* W = (m==0)?w11:(m==1)?w21:(m==2)?wa1:wb1;
        const int* M = (m < 2) ? m1 : nullptr;
        lo = l1val(W, M, o, 2*k2); hi = l1val(W, M, o, 2*k2+1);
      }
    } else if (i < OFF_HL){
      int loc = i - OFF_L2;
      int row = loc / 160, k2 = loc - row*160;
      int o = row >> 2, m = row & 3;
      if (o < 153){
        const float* W = (m==0)?w12:(m==1)?w22:(m==2)?wa2:wb2;
        const int* M = (m < 2) ? m2 : nullptr;
        lo = l2val(W, M, o, 2*k2); hi = l2val(W, M, o, 2*k2+1);
      }
    } else {
      ws[i] = 0u;                 // exchange arrays (h_rec(0)=0) + flags
      continue;
    }
    ws[i] = packbf(lo, hi);
  }
}

// ---------------- weight-stationary sliced persistent kernel ----------------
// grid 256 = 8 slices x 32 quads; slice s = bid&7 (-> XCD s under round-robin;
// perf-only), quad = bid>>3 owns batches 4q..4q+3. thread: b4 = tid&3 (batch),
// rr = tid>>2 (row in slice). Lanes 0-3 share a weight row -> 4-way dedup.
__global__ __launch_bounds__(1024) void liquid_rnn(
    const float* __restrict__ x, const float* __restrict__ dtp,
    const float* __restrict__ lstm_bi,
    const float* __restrict__ b10, const float* __restrict__ b20,
    const float* __restrict__ ba0, const float* __restrict__ bb0,
    const float* __restrict__ b11, const float* __restrict__ b21,
    const float* __restrict__ ba1, const float* __restrict__ bb1,
    const float* __restrict__ b12, const float* __restrict__ b22,
    const float* __restrict__ ba2, const float* __restrict__ bb2,
    u32* __restrict__ ws, float* __restrict__ out)
{
  __shared__ u32 xcS[4][272];     // activation staging (per local batch)

  const int tid  = threadIdx.x;
  const int bid  = blockIdx.x;
  const int s    = bid & 7;
  const int quad = bid >> 3;
  const int b4   = tid & 3;
  const int rr   = tid >> 2;            // 0..255
  const int batch= quad*4 + b4;

  u32* hlw  = ws + OFF_HL;
  u32* recw = ws + OFF_REC;
  u16* hl16 = (u16*)hlw;
  u16* rec16= (u16*)recw;
  u32* fl   = ws + OFF_SYNC + quad*(8*NFL);

  // ---- hoisted per-thread constants ----
  const int vA = s*64 + (rr >> 2);          // LSTM neuron of my row group
  const float lb = lstm_bi[vA + 512*(rr & 3)];
  int oB = 0; float biasB = 0.f;
  if (tid < 432){ int m = rr & 3; oB = 27*s + (rr >> 2);
    biasB = ((m==0)?b10:(m==1)?b20:(m==2)?ba0:bb0)[oB]; }
  int oC = 0; float biasC = 0.f;
  if (tid < 288){ int m = rr & 3; oC = 18*s + (rr >> 2);
    if (oC < 143) biasC = ((m==0)?b11:(m==1)?b21:(m==2)?ba1:bb1)[oC]; }
  int oD = 0; float biasD = 0.f;
  if (tid < 320){ int m = rr & 3; oD = 20*s + (rr >> 2);
    if (oD < 153) biasD = ((m==0)?b12:(m==1)?b22:(m==2)?ba2:bb2)[oD]; }

  for (int i = tid; i < 4*272; i += 1024) ((u32*)xcS)[i] = 0u;
  float creg = 0.f;
  __syncthreads();

  for (int t = 0; t < TT; ++t){
    const u32 vb = 4u*(u32)t;
    // ========== A staging: overlap with pending D(t-1) wait ==========
    if (tid < 20){                              // xt words 0..4
      int bb = tid/5, w = tid - bb*5;
      int bg = quad*4 + bb;
      float e0, e1;
      if (w < 4){ e0 = x[((size_t)bg*TT + t)*8 + 2*w]; e1 = x[((size_t)bg*TT + t)*8 + 2*w+1]; }
      else      { e0 = dtp[(size_t)bg*TT + t]; e1 = 0.f; }
      xcS[bb][w] = packbf(e0, e1);
    }
    if (tid < 720){                             // i0,i1 pairs: final since bars 2,3 of t-1
      int bb = tid/180, j = tid - bb*180;
      xcS[bb][5+j] = xload(&recw[(size_t)(quad*4+bb)*264 + j]);
    }
    bar_wait(fl, vb);                           // all slices' D(t-1) done (t=0: no-op)
    { int bb = tid >> 8, w = tid & 255;         // i2 pairs (words 180..255)
      if (w >= 180) xcS[bb][5+w] = xload(&recw[(size_t)(quad*4+bb)*264 + w]); }
    if (tid < 4) xcS[tid][261] = xload(&recw[(size_t)(quad*4+tid)*264 + 256]);
    __syncthreads();
    // ================= phase A: LSTM (rows 256s..256s+255) =================
    {
      float A = lb;
      const u32* wrow = ws + (size_t)(s*256 + rr)*LSW;
      #pragma unroll 4
      for (int g = 0; g < 68; ++g){
        uint4 wv = *(const uint4*)(wrow + (g<<2));
        uint4 av = *(const uint4*)&xcS[b4][g<<2];
        A = bdot(wv.x, av.x, A); A = bdot(wv.y, av.y, A);
        A = bdot(wv.z, av.z, A); A = bdot(wv.w, av.w, A);
      }
      float zig = __shfl_down(A, 4), zfg = __shfl_down(A, 8), zog = __shfl_down(A, 12);
      if (!(rr & 3)){
        creg = creg * sigm(zfg + 1.0f) + tanh_(A) * sigm(zig);
        float hl = tanh_(creg) * sigm(zog);
        xstore16(&hl16[(size_t)batch*528 + vA], f2bf(hl));
      }
    }
    bar_arrive(fl, s, vb+1);  bar_wait(fl, vb+1);
    // ================= phase B: CfC L0 (outputs 27s..27s+26) =================
    if (tid < 432){ int bb = tid/108, j = tid - bb*108;       // hl pairs 0..107
      xcS[bb][5+j] = xload(&hlw[(size_t)(quad*4+bb)*264 + j]); }
    __syncthreads();
    if (tid < 432){
      float A = biasB;
      const u32* wrow = ws + OFF_L0 + (size_t)(s*108 + rr)*128;
      #pragma unroll 2
      for (int g = 0; g < 30; ++g){
        uint4 wv = *(const uint4*)(wrow + (g<<2));
        uint4 av = *(const uint4*)&xcS[b4][g<<2];
        A = bdot(wv.x, av.x, A); A = bdot(wv.y, av.y, A);
        A = bdot(wv.z, av.z, A); A = bdot(wv.w, av.w, A);
      }
      float A1 = __shfl_down(A, 4), A2 = __shfl_down(A, 8), A3 = __shfl_down(A, 12);
      if (!(rr & 3)){
        float ti = sigm(A3 - A2);
        float o0 = tanh_(A)*(1.f - ti) + ti*tanh_(A1);
        xstore16(&rec16[(size_t)batch*528 + oB], f2bf(o0));
        if (t == TT-1) out[(size_t)batch*512 + oB] = o0;
      }
    }
    bar_arrive(fl, s, vb+2);  bar_wait(fl, vb+2);
    // ================= phase C: CfC L1 (outputs 18s.., guard <143) =================
    if (tid < 720){ int bb = tid/180, j = tid - bb*180;
      u32 v = (j < 108) ? xload(&recw[(size_t)(quad*4+bb)*264 + j])    // i0 pairs
                        : xload(&hlw[(size_t)(quad*4+bb)*264 + j]);    // hl 108..179
      xcS[bb][j] = v; }
    __syncthreads();
    if (tid < 288){
      float A = biasC;
      const u32* wrow = ws + OFF_L1 + (size_t)(s*72 + rr)*192;
      #pragma unroll 4
      for (int g = 0; g < 48; ++g){
        uint4 wv = *(const uint4*)(wrow + (g<<2));
        uint4 av = *(const uint4*)&xcS[b4][g<<2];
        A = bdot(wv.x, av.x, A); A = bdot(wv.y, av.y, A);
        A = bdot(wv.z, av.z, A); A = bdot(wv.w, av.w, A);
      }
      float A1 = __shfl_down(A, 4), A2 = __shfl_down(A, 8), A3 = __shfl_down(A, 12);
      if (!(rr & 3) && oC < 143){
        float ti = sigm(A3 - A2);
        float o0 = tanh_(A)*(1.f - ti) + ti*tanh_(A1);
        xstore16(&rec16[(size_t)batch*528 + 216 + oC], f2bf(o0));
        if (t == TT-1) out[(size_t)batch*512 + 216 + oC] = o0;
      }
    }
    bar_arrive(fl, s, vb+3);  bar_wait(fl, vb+3);
    // ================= phase D: CfC L2 (outputs 20s.., guard <153) =================
    if (tid < 596){ int bb = tid/149, j = tid - bb*149;
      u32 v;
      if (j < 72)      v = xload(&recw[(size_t)(quad*4+bb)*264 + 108 + j]);  // i1
      else if (j == 72) v = xload(&hlw[(size_t)(quad*4+bb)*264 + 179]);      // (h358,h359)
      else              v = xload(&hlw[(size_t)(quad*4+bb)*264 + 180 + (j-73)]);
      xcS[bb][j] = v; }
    __syncthreads();
    if (tid < 320){
      float A = biasD;
      const u32* wrow = ws + OFF_L2 + (size_t)(s*80 + rr)*160;
      #pragma unroll 4
      for (int g = 0; g < 40; ++g){
        uint4 wv = *(const uint4*)(wrow + (g<<2));
        uint4 av = *(const uint4*)&xcS[b4][g<<2];
        A = bdot(wv.x, av.x, A); A = bdot(wv.y, av.y, A);
        A = bdot(wv.z, av.z, A); A = bdot(wv.w, av.w, A);
      }
      float A1 = __shfl_down(A, 4), A2 = __shfl_down(A, 8), A3 = __shfl_down(A, 12);
      if (!(rr & 3) && oD < 153){
        float ti = sigm(A3 - A2);
        float o0 = tanh_(A)*(1.f - ti) + ti*tanh_(A1);
        xstore16(&rec16[(size_t)batch*528 + 360 + oD], f2bf(o0));
        if (t == TT-1) out[(size_t)batch*512 + 359 + oD] = o0;
      }
    }
    bar_arrive(fl, s, vb+4);   // wait deferred to next iteration's loop top
  }

  if (!(rr & 3)) out[65536 + (size_t)batch*512 + vA] = creg;
}

extern "C" void kernel_launch(void* const* d_in, const int* in_sizes, int n_in,
                              void* d_out, int out_size, void* d_ws, size_t ws_size,
                              hipStream_t stream)
{
  (void)in_sizes; (void)n_in; (void)out_size; (void)ws_size;
  const float* x   = (const float*)d_in[0];
  const float* dt  = (const float*)d_in[1];
  const float* wi  = (const float*)d_in[2];
  const float* wr  = (const float*)d_in[3];
  const float* bi  = (const float*)d_in[4];
  const float* w10 = (const float*)d_in[5];  const float* b10 = (const float*)d_in[6];
  const float* w20 = (const float*)d_in[7];  const float* b20 = (const float*)d_in[8];
  const float* wa0 = (const float*)d_in[9];  const float* ba0 = (const float*)d_in[10];
  const float* wb0 = (const float*)d_in[11]; const float* bb0 = (const float*)d_in[12];
  const float* w11 = (const float*)d_in[13]; const float* b11 = (const float*)d_in[14];
  const float* w21 = (const float*)d_in[15]; const float* b21 = (const float*)d_in[16];
  const float* wa1 = (const float*)d_in[17]; const float* ba1 = (const float*)d_in[18];
  const float* wb1 = (const float*)d_in[19]; const float* bb1 = (const float*)d_in[20];
  const float* w12 = (const float*)d_in[21]; const float* b12 = (const float*)d_in[22];
  const float* w22 = (const float*)d_in[23]; const float* b22 = (const float*)d_in[24];
  const float* wa2 = (const float*)d_in[25]; const float* ba2 = (const float*)d_in[26];
  const float* wb2 = (const float*)d_in[27]; const float* bb2 = (const float*)d_in[28];
  const int* m0 = (const int*)d_in[29];
  const int* m1 = (const int*)d_in[30];
  const int* m2 = (const int*)d_in[31];

  u32* ws    = (u32*)d_ws;         // needs WS_TOTAL*4 ≈ 3.63 MiB
  float* out = (float*)d_out;      // f32: h[128*512] then c[128*512]

  prep_kernel<<<dim3(931), dim3(1024), 0, stream>>>(
      wi, wr,
      w10,w20,wa0,wb0,m0,
      w11,w21,wa1,wb1,m1,
      w12,w22,wa2,wb2,m2,
      ws);

  liquid_rnn<<<dim3(256), dim3(1024), 0, stream>>>(
      x, dt, bi,
      b10,b20,ba0,bb0,
      b11,b21,ba1,bb1,
      b12,b22,ba2,bb2,
      ws, out);
}